// Round 1
// baseline (1016.970 us; speedup 1.0000x reference)
//
#include <hip/hip_runtime.h>
#include <hip/hip_bf16.h>
#include <hip/hip_cooperative_groups.h>

namespace cg = cooperative_groups;

#define N_NODES 131072
#define B_SEG   2048
#define F_DIM   200
#define K_DIM   608      // 400 (q_star) + 200 (h) + 8 zero pad = 19*32
#define NEG_INF (-3.4e38f)
#define GRID    1024     // cooperative grid: 4 blocks/CU * 256 CUs

typedef __attribute__((ext_vector_type(8))) short bf16x8;
typedef __attribute__((ext_vector_type(4))) float f32x4;

__device__ __forceinline__ float b2f(unsigned short u) {
  union { unsigned int i; float f; } v; v.i = ((unsigned int)u) << 16; return v.f;
}
__device__ __forceinline__ unsigned short f2bu(float f) {
  __hip_bfloat16 h = __float2bfloat16(f);
  return *reinterpret_cast<unsigned short*>(&h);
}
__device__ __forceinline__ float sigmoidf_(float x) { return 1.f / (1.f + __expf(-x)); }
// tanh via hw exp: exact at +-inf saturation, ~1e-6 rel error (bf16 noise dominates)
__device__ __forceinline__ float tanhf_(float x) {
  float e = __expf(2.f * x);
  return 1.f - 2.f / (1.f + e);
}
// first index i with batch[i] >= target (batch sorted ascending)
__device__ __forceinline__ int lower_bound_batch(const int* __restrict__ batch, int target) {
  int lo = 0, hi = N_NODES;
  while (lo < hi) {
    int mid = (lo + hi) >> 1;
    if (batch[mid] < target) lo = mid + 1; else hi = mid;
  }
  return lo;
}

// =====================================================================
// Cooperative mega-kernel: setup + init + 3x(gates GEMM ; fused LSTM+attn)
// Block b owns segments 2b and 2b+1; LSTM c-state lives in registers.
// =====================================================================
__global__ __launch_bounds__(256, 4) void mega_kernel(
    const float* __restrict__ xf, const int* __restrict__ batch,
    const float* __restrict__ cosc, const float* __restrict__ qs0,
    const float* __restrict__ Wih, const float* __restrict__ Whh,
    const float* __restrict__ bih, const float* __restrict__ bhh,
    unsigned short* __restrict__ xb, unsigned short* __restrict__ A,
    unsigned short* __restrict__ Wc, float* __restrict__ gates,
    float* __restrict__ bsum, float* __restrict__ out) {
  cg::grid_group grid = cg::this_grid();
  __shared__ float q_s[F_DIM];
  __shared__ float rpart[8][F_DIM];
  __shared__ float redm[8], redl[8];
  __shared__ int sb[3];
  int b = blockIdx.x, tid = threadIdx.x;

  // ---------------- phase 0: bounds search + W/bias pack + init ----------------
  if (tid < 3) sb[tid] = lower_bound_batch(batch, 2 * b + tid);
  // grid-strided weight pack (waves 1-3 overlap wave 0's binary search)
  for (int idx = b * 256 + tid; idx < 832 * K_DIM; idx += GRID * 256) {
    int row = idx / K_DIM, k = idx - row * K_DIM;
    float v = 0.f;
    if (row < 800) {
      if (k < 400)      v = Wih[row * 400 + k];
      else if (k < 600) v = Whh[row * 200 + (k - 400)];
    }
    Wc[idx] = f2bu(v);
  }
  for (int i = b * 256 + tid; i < 800; i += GRID * 256) bsum[i] = bih[i] + bhh[i];
  __syncthreads();
  int start0 = sb[0], end0 = sb[1], end1 = sb[2];

  // init both segments: x -> bf16 xb, a_sit = sum(cos*x), qs0 pack into A row
  for (int si = 0; si < 2; si++) {
    int seg = 2 * b + si;
    int st = si ? end0 : start0, en = si ? end1 : end0;
    int n = en - st;
    unsigned short* Arow = A + (size_t)seg * K_DIM;
    int rgrp = tid / 50, col4 = tid - rgrp * 50;   // rgrp 0..4 active, col4 0..49
    float a0 = 0.f, a1 = 0.f, a2 = 0.f, a3 = 0.f;
    if (rgrp < 5) {
      for (int r = rgrp; r < n; r += 5) {
        float4 v = *(const float4*)(xf + (size_t)(st + r) * F_DIM + 4 * col4);
        ushort4 o; o.x = f2bu(v.x); o.y = f2bu(v.y); o.z = f2bu(v.z); o.w = f2bu(v.w);
        *(ushort4*)(xb + (size_t)(st + r) * F_DIM + 4 * col4) = o;
        float cv = cosc[st + r];
        a0 += cv * b2f(o.x); a1 += cv * b2f(o.y);
        a2 += cv * b2f(o.z); a3 += cv * b2f(o.w);
      }
      rpart[rgrp][4 * col4]     = a0;
      rpart[rgrp][4 * col4 + 1] = a1;
      rpart[rgrp][4 * col4 + 2] = a2;
      rpart[rgrp][4 * col4 + 3] = a3;
    }
    if (tid < 100) {                       // qs0 row: 400 f32 -> 400 bf16
      float4 v = *(const float4*)(qs0 + (size_t)seg * 400 + 4 * tid);
      ushort4 o; o.x = f2bu(v.x); o.y = f2bu(v.y); o.z = f2bu(v.z); o.w = f2bu(v.w);
      *(ushort4*)(Arow + 4 * tid) = o;
    }
    if (tid < 8) Arow[600 + tid] = 0;
    __syncthreads();
    if (tid < F_DIM) {
      float acc = rpart[0][tid] + rpart[1][tid] + rpart[2][tid] + rpart[3][tid]
                + rpart[4][tid];
      Arow[400 + tid] = f2bu(acc);
    }
    __syncthreads();                       // rpart reused by next segment / attn
  }

  float c0 = 0.f, c1 = 0.f;                // LSTM cell state, in registers
  grid.sync();

  // ---------------- 3 processing steps ----------------
  for (int s = 0; s < 3; s++) {
    // ---- gates GEMM: 832 tile jobs (BM=32, BN=64), barrier-free ----
    if (b < 832) {
      int bm = (b & 63) * 32, bn = (b >> 6) * 64;
      int wave = tid >> 6, lane = tid & 63;
      int quad = lane >> 4, col = lane & 15;
      int strip = wave >> 1;               // 0..1 : 16-row strip
      int tp = (wave & 1) * 2;             // 0 or 2 : N-tile pair
      f32x4 acc[2];
      acc[0] = (f32x4){0.f, 0.f, 0.f, 0.f};
      acc[1] = (f32x4){0.f, 0.f, 0.f, 0.f};
      const unsigned short* Ap = A + (size_t)(bm + strip * 16 + col) * K_DIM + quad * 8;
      const unsigned short* Wp = Wc + (size_t)(bn + col) * K_DIM + quad * 8;
#pragma unroll
      for (int k0 = 0; k0 < K_DIM; k0 += 32) {
        bf16x8 af = *(const bf16x8*)(Ap + k0);
#pragma unroll
        for (int t = 0; t < 2; t++) {
          bf16x8 bfr = *(const bf16x8*)(Wp + (size_t)(tp + t) * 16 * K_DIM + k0);
          acc[t] = __builtin_amdgcn_mfma_f32_16x16x32_bf16(af, bfr, acc[t], 0, 0, 0);
        }
      }
#pragma unroll
      for (int t = 0; t < 2; t++) {
        int gn = bn + (tp + t) * 16 + col;
        if (gn < 800) {
#pragma unroll
          for (int r = 0; r < 4; r++) {
            int gm = bm + strip * 16 + quad * 4 + r;
            gates[(size_t)gm * 800 + gn] = acc[t][r];
          }
        }
      }
    }
    grid.sync();

    // ---- fused LSTM cell + online-softmax attention, 2 segments ----
    for (int si = 0; si < 2; si++) {
      int seg = 2 * b + si;
      int st = si ? end0 : start0, en = si ? end1 : end0;
      int n = en - st;
      unsigned short* Arow = A + (size_t)seg * K_DIM;
      float cprev = si ? c1 : c0;
      float cnew = cprev;
      if (tid < F_DIM) {
        const float* g = gates + (size_t)seg * 800;
        float gi = g[tid]       + bsum[tid];
        float gf = g[200 + tid] + bsum[200 + tid];
        float gg = g[400 + tid] + bsum[400 + tid];
        float go = g[600 + tid] + bsum[600 + tid];
        float cn = sigmoidf_(gf) * cprev + sigmoidf_(gi) * tanhf_(gg);
        float hn = sigmoidf_(go) * tanhf_(cn);
        cnew = cn;
        q_s[tid] = hn;
        if (s < 2) {
          unsigned short hb = f2bu(hn);
          Arow[tid] = hb;                  // q part of next q_star
          Arow[400 + tid] = hb;            // hidden for next cell
        }
      }
      if (si) c1 = cnew; else c0 = cnew;
      __syncthreads();
      int wave = tid >> 6, lane = tid & 63;
      int half = lane >> 5, hl = lane & 31;  // 32-lane half-wave
      int hw = wave * 2 + half;              // 0..7 : row owner
      bool act = (hl < 25);                  // 25 lanes x 8 elems = 200 features
      float q0=0,q1=0,q2=0,q3=0,q4=0,q5=0,q6=0,q7=0;
      if (act) {
        q0 = q_s[8*hl];   q1 = q_s[8*hl+1]; q2 = q_s[8*hl+2]; q3 = q_s[8*hl+3];
        q4 = q_s[8*hl+4]; q5 = q_s[8*hl+5]; q6 = q_s[8*hl+6]; q7 = q_s[8*hl+7];
      }
      const unsigned short* xp = xb + (size_t)st * F_DIM + 8 * hl;
      float m = NEG_INF, l = 0.f;
      float a0=0,a1=0,a2=0,a3=0,a4=0,a5=0,a6=0,a7=0;
      for (int r = hw; r < n; r += 8) {
        float x0=0,x1=0,x2=0,x3=0,x4=0,x5=0,x6=0,x7=0;
        float p = 0.f;
        if (act) {
          uint4 v = *(const uint4*)(xp + (size_t)r * F_DIM);
          x0 = b2f((unsigned short)(v.x & 0xffff)); x1 = b2f((unsigned short)(v.x >> 16));
          x2 = b2f((unsigned short)(v.y & 0xffff)); x3 = b2f((unsigned short)(v.y >> 16));
          x4 = b2f((unsigned short)(v.z & 0xffff)); x5 = b2f((unsigned short)(v.z >> 16));
          x6 = b2f((unsigned short)(v.w & 0xffff)); x7 = b2f((unsigned short)(v.w >> 16));
          p = q0*x0 + q1*x1 + q2*x2 + q3*x3 + q4*x4 + q5*x5 + q6*x6 + q7*x7;
        }
#pragma unroll
        for (int off = 16; off; off >>= 1) p += __shfl_xor(p, off, 32);
        float e = p;
        float mn = fmaxf(m, e);
        float fac = __expf(m - mn);        // first iter: exp(-inf)=0
        float w  = __expf(e - mn);
        l  = l * fac + w;
        a0 = a0*fac + w*x0; a1 = a1*fac + w*x1; a2 = a2*fac + w*x2; a3 = a3*fac + w*x3;
        a4 = a4*fac + w*x4; a5 = a5*fac + w*x5; a6 = a6*fac + w*x6; a7 = a7*fac + w*x7;
        m = mn;
      }
      if (hl == 0) redm[hw] = m;
      __syncthreads();
      float M = fmaxf(fmaxf(fmaxf(redm[0], redm[1]), fmaxf(redm[2], redm[3])),
                      fmaxf(fmaxf(redm[4], redm[5]), fmaxf(redm[6], redm[7])));
      float facw = (m > NEG_INF) ? __expf(m - M) : 0.f;
      if (hl == 0) redl[hw] = l * facw;
      if (act) {
        float* rp = &rpart[hw][8 * hl];
        rp[0] = a0*facw; rp[1] = a1*facw; rp[2] = a2*facw; rp[3] = a3*facw;
        rp[4] = a4*facw; rp[5] = a5*facw; rp[6] = a6*facw; rp[7] = a7*facw;
      }
      __syncthreads();
      float L = redl[0]+redl[1]+redl[2]+redl[3]+redl[4]+redl[5]+redl[6]+redl[7];
      float inv = (L > 0.f) ? 1.f / L : 0.f;
      if (tid < F_DIM) {
        float rv = (rpart[0][tid]+rpart[1][tid]+rpart[2][tid]+rpart[3][tid]
                  + rpart[4][tid]+rpart[5][tid]+rpart[6][tid]+rpart[7][tid]) * inv;
        if (s < 2) {
          Arow[200 + tid] = f2bu(rv);
        } else {
          out[(size_t)seg * 400 + tid]       = q_s[tid];
          out[(size_t)seg * 400 + 200 + tid] = rv;
        }
      }
      __syncthreads();                     // shared arrays reused next segment
    }
    if (s < 2) grid.sync();
  }
}

// =====================================================================
// Fallback path: the previous 8-dispatch pipeline (verbatim), used only
// if hipLaunchCooperativeKernel cannot be enqueued/captured.
// =====================================================================
__global__ __launch_bounds__(256) void setup_kernel(
    const float* __restrict__ Wih, const float* __restrict__ Whh,
    const float* __restrict__ bih, const float* __restrict__ bhh,
    const int* __restrict__ batch, unsigned short* __restrict__ Wc,
    float* __restrict__ bsum, int* __restrict__ seg_off) {
  int bid = blockIdx.x, tid = threadIdx.x;
  if (bid < 1976) {
    int idx = bid * 256 + tid;
    int row = idx / K_DIM, k = idx - row * K_DIM;
    float v = 0.f;
    if (row < 800) {
      if (k < 400)      v = Wih[row * 400 + k];
      else if (k < 600) v = Whh[row * 200 + (k - 400)];
    }
    Wc[idx] = f2bu(v);
  } else if (bid < 1976 + 512) {
    int i = (bid - 1976) * 256 + tid;
    int v  = batch[i];
    int pv = (i == 0) ? -1 : batch[i - 1];
    for (int b = pv + 1; b <= v; b++) seg_off[b] = i;
  } else {
    int idx = (bid - 2488) * 256 + tid;
    if (idx < 800) bsum[idx] = bih[idx] + bhh[idx];
    else if (idx == 800) {
      int last = batch[N_NODES - 1];
      for (int b = last + 1; b <= B_SEG; b++) seg_off[b] = N_NODES;
    }
  }
}

__global__ __launch_bounds__(256) void init_kernel(
    const float* __restrict__ xf, const int* __restrict__ seg_off,
    const float* __restrict__ cosc, const float* __restrict__ qs0,
    unsigned short* __restrict__ xb, unsigned short* __restrict__ A) {
  __shared__ float rpart[5][F_DIM];
  int b = blockIdx.x, tid = threadIdx.x;
  int start = seg_off[b], end = seg_off[b + 1];
  int n = end - start;
  unsigned short* Arow = A + (size_t)b * K_DIM;
  int rgrp = tid / 50, col4 = tid - rgrp * 50;
  float a0 = 0.f, a1 = 0.f, a2 = 0.f, a3 = 0.f;
  if (rgrp < 5) {
    for (int r = rgrp; r < n; r += 5) {
      float4 v = *(const float4*)(xf + (size_t)(start + r) * F_DIM + 4 * col4);
      ushort4 o; o.x = f2bu(v.x); o.y = f2bu(v.y); o.z = f2bu(v.z); o.w = f2bu(v.w);
      *(ushort4*)(xb + (size_t)(start + r) * F_DIM + 4 * col4) = o;
      float cv = cosc[start + r];
      a0 += cv * b2f(o.x); a1 += cv * b2f(o.y);
      a2 += cv * b2f(o.z); a3 += cv * b2f(o.w);
    }
    rpart[rgrp][4 * col4]     = a0;
    rpart[rgrp][4 * col4 + 1] = a1;
    rpart[rgrp][4 * col4 + 2] = a2;
    rpart[rgrp][4 * col4 + 3] = a3;
  }
  if (tid < 100) {
    float4 v = *(const float4*)(qs0 + (size_t)b * 400 + 4 * tid);
    ushort4 o; o.x = f2bu(v.x); o.y = f2bu(v.y); o.z = f2bu(v.z); o.w = f2bu(v.w);
    *(ushort4*)(Arow + 4 * tid) = o;
  }
  if (tid < 8) Arow[600 + tid] = 0;
  __syncthreads();
  if (tid < F_DIM) {
    float acc = rpart[0][tid] + rpart[1][tid] + rpart[2][tid] + rpart[3][tid]
              + rpart[4][tid];
    Arow[400 + tid] = f2bu(acc);
  }
}

__global__ __launch_bounds__(256) void gemm_gates(
    const unsigned short* __restrict__ A, const unsigned short* __restrict__ W,
    float* __restrict__ gates) {
  int tid = threadIdx.x;
  int bm = blockIdx.x * 32, bn = blockIdx.y * 64;
  int wave = tid >> 6, lane = tid & 63;
  int quad = lane >> 4, col = lane & 15;
  int strip = wave >> 1;
  int tp = (wave & 1) * 2;
  f32x4 acc[2];
  acc[0] = (f32x4){0.f, 0.f, 0.f, 0.f};
  acc[1] = (f32x4){0.f, 0.f, 0.f, 0.f};
  const unsigned short* Ap = A + (size_t)(bm + strip * 16 + col) * K_DIM + quad * 8;
  const unsigned short* Wp = W + (size_t)(bn + col) * K_DIM + quad * 8;
#pragma unroll
  for (int k0 = 0; k0 < K_DIM; k0 += 32) {
    bf16x8 af = *(const bf16x8*)(Ap + k0);
#pragma unroll
    for (int t = 0; t < 2; t++) {
      bf16x8 bfr = *(const bf16x8*)(Wp + (size_t)(tp + t) * 16 * K_DIM + k0);
      acc[t] = __builtin_amdgcn_mfma_f32_16x16x32_bf16(af, bfr, acc[t], 0, 0, 0);
    }
  }
#pragma unroll
  for (int t = 0; t < 2; t++) {
    int gn = bn + (tp + t) * 16 + col;
    if (gn < 800) {
#pragma unroll
      for (int r = 0; r < 4; r++) {
        int gm = bm + strip * 16 + quad * 4 + r;
        gates[(size_t)gm * 800 + gn] = acc[t][r];
      }
    }
  }
}

__global__ __launch_bounds__(256) void attn_fused(
    const unsigned short* __restrict__ xb, const int* __restrict__ seg_off,
    const float* __restrict__ gates, const float* __restrict__ bsum,
    float* __restrict__ cvec, unsigned short* __restrict__ A,
    float* __restrict__ out, int step) {
  __shared__ float q_s[F_DIM];
  __shared__ float rpart[8][F_DIM];
  __shared__ float redm[8], redl[8];
  int b = blockIdx.x, tid = threadIdx.x;
  int start = seg_off[b], end = seg_off[b + 1];
  int n = end - start;
  unsigned short* Arow = A + (size_t)b * K_DIM;
  if (tid < F_DIM) {
    int f = tid;
    const float* g = gates + (size_t)b * 800;
    float gi = g[f]       + bsum[f];
    float gf = g[200 + f] + bsum[200 + f];
    float gg = g[400 + f] + bsum[400 + f];
    float go = g[600 + f] + bsum[600 + f];
    float cp = (step > 0) ? cvec[(size_t)b * F_DIM + f] : 0.f;
    float cn = sigmoidf_(gf) * cp + sigmoidf_(gi) * tanhf(gg);
    float hn = sigmoidf_(go) * tanhf(cn);
    cvec[(size_t)b * F_DIM + f] = cn;
    q_s[f] = hn;
    if (step < 2) {
      unsigned short hb = f2bu(hn);
      Arow[f] = hb;
      Arow[400 + f] = hb;
    }
  }
  __syncthreads();
  int wave = tid >> 6, lane = tid & 63;
  int half = lane >> 5, hl = lane & 31;
  int hw = wave * 2 + half;
  bool act = (hl < 25);
  float q0=0,q1=0,q2=0,q3=0,q4=0,q5=0,q6=0,q7=0;
  if (act) {
    q0 = q_s[8*hl];   q1 = q_s[8*hl+1]; q2 = q_s[8*hl+2]; q3 = q_s[8*hl+3];
    q4 = q_s[8*hl+4]; q5 = q_s[8*hl+5]; q6 = q_s[8*hl+6]; q7 = q_s[8*hl+7];
  }
  const unsigned short* xp = xb + (size_t)start * F_DIM + 8 * hl;
  float m = NEG_INF, l = 0.f;
  float a0=0,a1=0,a2=0,a3=0,a4=0,a5=0,a6=0,a7=0;
  for (int r = hw; r < n; r += 8) {
    float x0=0,x1=0,x2=0,x3=0,x4=0,x5=0,x6=0,x7=0;
    float p = 0.f;
    if (act) {
      uint4 v = *(const uint4*)(xp + (size_t)r * F_DIM);
      x0 = b2f((unsigned short)(v.x & 0xffff)); x1 = b2f((unsigned short)(v.x >> 16));
      x2 = b2f((unsigned short)(v.y & 0xffff)); x3 = b2f((unsigned short)(v.y >> 16));
      x4 = b2f((unsigned short)(v.z & 0xffff)); x5 = b2f((unsigned short)(v.z >> 16));
      x6 = b2f((unsigned short)(v.w & 0xffff)); x7 = b2f((unsigned short)(v.w >> 16));
      p = q0*x0 + q1*x1 + q2*x2 + q3*x3 + q4*x4 + q5*x5 + q6*x6 + q7*x7;
    }
#pragma unroll
    for (int off = 16; off; off >>= 1) p += __shfl_xor(p, off, 32);
    float e = p;
    float mn = fmaxf(m, e);
    float fac = __expf(m - mn);
    float w  = __expf(e - mn);
    l  = l * fac + w;
    a0 = a0*fac + w*x0; a1 = a1*fac + w*x1; a2 = a2*fac + w*x2; a3 = a3*fac + w*x3;
    a4 = a4*fac + w*x4; a5 = a5*fac + w*x5; a6 = a6*fac + w*x6; a7 = a7*fac + w*x7;
    m = mn;
  }
  if (hl == 0) redm[hw] = m;
  __syncthreads();
  float M = fmaxf(fmaxf(fmaxf(redm[0], redm[1]), fmaxf(redm[2], redm[3])),
                  fmaxf(fmaxf(redm[4], redm[5]), fmaxf(redm[6], redm[7])));
  float facw = (m > NEG_INF) ? __expf(m - M) : 0.f;
  if (hl == 0) redl[hw] = l * facw;
  if (act) {
    float* rp = &rpart[hw][8 * hl];
    rp[0] = a0*facw; rp[1] = a1*facw; rp[2] = a2*facw; rp[3] = a3*facw;
    rp[4] = a4*facw; rp[5] = a5*facw; rp[6] = a6*facw; rp[7] = a7*facw;
  }
  __syncthreads();
  float L = redl[0]+redl[1]+redl[2]+redl[3]+redl[4]+redl[5]+redl[6]+redl[7];
  float inv = (L > 0.f) ? 1.f / L : 0.f;
  if (tid < F_DIM) {
    float rv = (rpart[0][tid]+rpart[1][tid]+rpart[2][tid]+rpart[3][tid]
              + rpart[4][tid]+rpart[5][tid]+rpart[6][tid]+rpart[7][tid]) * inv;
    if (step < 2) {
      Arow[200 + tid] = f2bu(rv);
    } else {
      out[(size_t)b * 400 + tid]       = q_s[tid];
      out[(size_t)b * 400 + 200 + tid] = rv;
    }
  }
}

extern "C" void kernel_launch(void* const* d_in, const int* in_sizes, int n_in,
                              void* d_out, int out_size, void* d_ws, size_t ws_size,
                              hipStream_t stream) {
  const float* x    = (const float*)d_in[0];
  const int*   batch= (const int*)d_in[1];
  const float* cosc = (const float*)d_in[2];
  const float* qs0  = (const float*)d_in[3];
  const float* Wih  = (const float*)d_in[4];
  const float* Whh  = (const float*)d_in[5];
  const float* bih  = (const float*)d_in[6];
  const float* bhh  = (const float*)d_in[7];
  char* ws = (char*)d_ws;
  // ws layout (bytes, 16B aligned):
  unsigned short* xb   = (unsigned short*)(ws);               // 131072*200*2 = 52,428,800
  unsigned short* A    = (unsigned short*)(ws + 52428800);    // 2048*608*2   =  2,490,368
  unsigned short* Wc   = (unsigned short*)(ws + 54919168);    // 832*608*2    =  1,011,712
  float*          gates= (float*)(ws + 55930880);             // 2048*800*4   =  6,553,600
  float*          cvec = (float*)(ws + 62484480);             // 2048*200*4 (fallback only)
  float*          bsum = (float*)(ws + 64122880);             // 800*4
  int*            soff = (int*)(ws + 64126080);               // 2052*4 (fallback only)
  float*          outp = (float*)d_out;

  void* args[] = {(void*)&x, (void*)&batch, (void*)&cosc, (void*)&qs0,
                  (void*)&Wih, (void*)&Whh, (void*)&bih, (void*)&bhh,
                  (void*)&xb, (void*)&A, (void*)&Wc, (void*)&gates,
                  (void*)&bsum, (void*)&outp};
  hipError_t err = hipLaunchCooperativeKernel((const void*)mega_kernel,
                                              dim3(GRID), dim3(256),
                                              (void**)args, 0, stream);
  if (err != hipSuccess) {
    // fallback: previous known-good 8-dispatch pipeline
    setup_kernel<<<2492, 256, 0, stream>>>(Wih, Whh, bih, bhh, batch, Wc, bsum, soff);
    init_kernel<<<B_SEG, 256, 0, stream>>>(x, soff, cosc, qs0, xb, A);
    for (int s = 0; s < 3; s++) {
      gemm_gates<<<dim3(64, 13), 256, 0, stream>>>(A, Wc, gates);
      attn_fused<<<B_SEG, 256, 0, stream>>>(xb, soff, gates, bsum, cvec, A, outp, s);
    }
  }
}

// Round 3
// 318.413 us; speedup vs baseline: 3.1939x; 3.1939x over previous
//
#include <hip/hip_runtime.h>
#include <hip/hip_bf16.h>

#define N_NODES 131072
#define B_SEG   2048
#define F_DIM   200
#define K_DIM   608      // 400 (q_star) + 200 (h) + 8 zero pad = 19*32
#define K_PAD   616      // LDS row stride: 1232B = 16B-aligned, bank-spread
#define NEG_INF (-3.4e38f)
#define SEGS    8
#define MAIN_GRID (B_SEG / SEGS)   // 256 blocks, 1 per CU
#define MAIN_THREADS 512           // 8 waves

typedef __attribute__((ext_vector_type(8))) short bf16x8;
typedef __attribute__((ext_vector_type(4))) float f32x4;

__device__ __forceinline__ float b2f(unsigned short u) {
  union { unsigned int i; float f; } v; v.i = ((unsigned int)u) << 16; return v.f;
}
__device__ __forceinline__ unsigned short f2bu(float f) {
  __hip_bfloat16 h = __float2bfloat16(f);
  return *reinterpret_cast<unsigned short*>(&h);
}
__device__ __forceinline__ float sigmoidf_(float x) { return 1.f / (1.f + __expf(-x)); }
__device__ __forceinline__ float tanhf_(float x) {
  float e = __expf(2.f * x);
  return 1.f - 2.f / (1.f + e);
}
// first index i with batch[i] >= target (batch sorted ascending)
__device__ __forceinline__ int lower_bound_batch(const int* __restrict__ batch, int target) {
  int lo = 0, hi = N_NODES;
  while (lo < hi) {
    int mid = (lo + hi) >> 1;
    if (batch[mid] < target) lo = mid + 1; else hi = mid;
  }
  return lo;
}

// ---------------------------------------------------------------------
// init: W pack + bias sum + per-segment bounds (binary search) + x->bf16
//       + a_sit segment-sum + qs0 pack  -> A[2048][608] global
// grid 2048 x 256 (block b owns segment b)
// ---------------------------------------------------------------------
__global__ __launch_bounds__(256) void init_kernel(
    const float* __restrict__ xf, const int* __restrict__ batch,
    const float* __restrict__ cosc, const float* __restrict__ qs0,
    const float* __restrict__ Wih, const float* __restrict__ Whh,
    const float* __restrict__ bih, const float* __restrict__ bhh,
    unsigned short* __restrict__ xb, unsigned short* __restrict__ A,
    unsigned short* __restrict__ Wc, float* __restrict__ bsum,
    int* __restrict__ seg_off) {
  __shared__ float rpart[5][F_DIM];
  __shared__ int sb[2];
  int b = blockIdx.x, tid = threadIdx.x;
  if (tid < 2) sb[tid] = lower_bound_batch(batch, b + tid);
  // grid-strided packs: 2048*256 = 524288 threads >= 832*608 = 505856 (1 iter)
  int idx = b * 256 + tid;
  if (idx < 832 * K_DIM) {
    int row = idx / K_DIM, k = idx - row * K_DIM;
    float v = 0.f;
    if (row < 800) {
      if (k < 400)      v = Wih[row * 400 + k];
      else if (k < 600) v = Whh[row * 200 + (k - 400)];
    }
    Wc[idx] = f2bu(v);
  }
  if (idx < 800) bsum[idx] = bih[idx] + bhh[idx];
  __syncthreads();
  int start = sb[0], end = sb[1];
  int n = end - start;
  if (tid == 0) {
    seg_off[b] = start;
    if (b == 0) seg_off[B_SEG] = N_NODES;
  }
  unsigned short* Arow = A + (size_t)b * K_DIM;
  int rgrp = tid / 50, col4 = tid - rgrp * 50;   // rgrp 0..4 active, col4 0..49
  float a0 = 0.f, a1 = 0.f, a2 = 0.f, a3 = 0.f;
  if (rgrp < 5) {
    for (int r = rgrp; r < n; r += 5) {
      float4 v = *(const float4*)(xf + (size_t)(start + r) * F_DIM + 4 * col4);
      ushort4 o; o.x = f2bu(v.x); o.y = f2bu(v.y); o.z = f2bu(v.z); o.w = f2bu(v.w);
      *(ushort4*)(xb + (size_t)(start + r) * F_DIM + 4 * col4) = o;
      float cv = cosc[start + r];
      a0 += cv * b2f(o.x); a1 += cv * b2f(o.y);
      a2 += cv * b2f(o.z); a3 += cv * b2f(o.w);
    }
    rpart[rgrp][4 * col4]     = a0;
    rpart[rgrp][4 * col4 + 1] = a1;
    rpart[rgrp][4 * col4 + 2] = a2;
    rpart[rgrp][4 * col4 + 3] = a3;
  }
  if (tid < 100) {                       // qs0 row: 400 f32 -> 400 bf16
    float4 v = *(const float4*)(qs0 + (size_t)b * 400 + 4 * tid);
    ushort4 o; o.x = f2bu(v.x); o.y = f2bu(v.y); o.z = f2bu(v.z); o.w = f2bu(v.w);
    *(ushort4*)(Arow + 4 * tid) = o;
  }
  if (tid < 8) Arow[600 + tid] = 0;
  __syncthreads();
  if (tid < F_DIM) {
    float acc = rpart[0][tid] + rpart[1][tid] + rpart[2][tid] + rpart[3][tid]
              + rpart[4][tid];
    Arow[400 + tid] = f2bu(acc);
  }
}

// ---------------------------------------------------------------------
// main: 3 steps, fully block-local. Block owns 8 segments.
// Per step: gates GEMM (MFMA, M=16 tile w/ 8 used rows) -> LDS,
//           LSTM cell (c-state in LDS), online-softmax attention
//           (16 half-waves per segment, 1-deep prefetch).
// ---------------------------------------------------------------------
__global__ __launch_bounds__(512, 2) void main_kernel(
    const unsigned short* __restrict__ xb, const int* __restrict__ seg_off,
    const unsigned short* __restrict__ Aglob, const unsigned short* __restrict__ Wc,
    const float* __restrict__ bsum, float* __restrict__ out) {
  __shared__ unsigned short ArowsS[SEGS][K_PAD];   //  9,856 B
  __shared__ float gatesS[SEGS][800];              // 25,600 B
  __shared__ float cS[SEGS][F_DIM];                //  6,400 B
  __shared__ float qS[SEGS][F_DIM];                //  6,400 B
  __shared__ float rpart[16][202];                 // 12,928 B (202: bank-spread)
  __shared__ float redm[16], redl[16];
  __shared__ int sbound[SEGS + 1];
  int tid = threadIdx.x;
  int seg0 = blockIdx.x * SEGS;
  if (tid < SEGS + 1) sbound[tid] = seg_off[seg0 + tid];
  {                                      // A rows: global -> LDS (wave w = seg w)
    int wv = tid >> 6, lane = tid & 63;
    const unsigned short* src = Aglob + (size_t)(seg0 + wv) * K_DIM;
    for (int k = lane; k < K_DIM; k += 64) ArowsS[wv][k] = src[k];
  }
  for (int it = tid; it < SEGS * F_DIM; it += MAIN_THREADS) ((float*)cS)[it] = 0.f;
  __syncthreads();

  int lane = tid & 63, wv = tid >> 6;
  int quad = lane >> 4, col = lane & 15;
  int hw = tid >> 5, hl = tid & 31;       // 16 half-waves
  bool act = (hl < 25);                   // 25 lanes x 8 feats = 200

  for (int s = 0; s < 3; s++) {
    // ---- gates GEMM: gatesS[8][800] = Arows[8][608] * Wc[800][608]^T ----
    bf16x8 afr[19];
#pragma unroll
    for (int kk = 0; kk < 19; kk++)
      afr[kk] = *(const bf16x8*)(&ArowsS[lane & 7][kk * 32 + quad * 8]);
    for (int nt = wv; nt < 50; nt += 8) { // 50 N-tiles of 16 over 8 waves
      f32x4 acc = (f32x4){0.f, 0.f, 0.f, 0.f};
      const unsigned short* Wp = Wc + (size_t)(nt * 16 + col) * K_DIM + quad * 8;
#pragma unroll
      for (int kk = 0; kk < 19; kk++) {
        bf16x8 bfr = *(const bf16x8*)(Wp + kk * 32);
        acc = __builtin_amdgcn_mfma_f32_16x16x32_bf16(afr[kk], bfr, acc, 0, 0, 0);
      }
      if (quad < 2) {                     // C rows 0..7 valid (rows 8..15 dup)
#pragma unroll
        for (int r = 0; r < 4; r++) gatesS[quad * 4 + r][nt * 16 + col] = acc[r];
      }
    }
    __syncthreads();
    // ---- LSTM cell: 8 segs x 200 feats ----
    for (int it = tid; it < SEGS * F_DIM; it += MAIN_THREADS) {
      int si = it / F_DIM, f = it - si * F_DIM;
      float gi = gatesS[si][f]       + bsum[f];
      float gf = gatesS[si][200 + f] + bsum[200 + f];
      float gg = gatesS[si][400 + f] + bsum[400 + f];
      float go = gatesS[si][600 + f] + bsum[600 + f];
      float cp = cS[si][f];
      float cn = sigmoidf_(gf) * cp + sigmoidf_(gi) * tanhf_(gg);
      float hn = sigmoidf_(go) * tanhf_(cn);
      cS[si][f] = cn;
      qS[si][f] = hn;
      if (s < 2) {
        unsigned short hb = f2bu(hn);
        ArowsS[si][f] = hb;               // q part of next q_star
        ArowsS[si][400 + f] = hb;         // hidden for next cell
      } else {
        out[(size_t)(seg0 + si) * 400 + f] = hn;
      }
    }
    __syncthreads();
    // ---- attention: one segment at a time, 16 half-waves ----
    for (int si = 0; si < SEGS; si++) {
      int st = sbound[si], n = sbound[si + 1] - st;
      float q0=0,q1=0,q2=0,q3=0,q4=0,q5=0,q6=0,q7=0;
      if (act) {
        float4 qa = *(const float4*)&qS[si][8 * hl];
        float4 qb = *(const float4*)&qS[si][8 * hl + 4];
        q0=qa.x; q1=qa.y; q2=qa.z; q3=qa.w; q4=qb.x; q5=qb.y; q6=qb.z; q7=qb.w;
      }
      const unsigned short* xp = xb + (size_t)st * F_DIM + 8 * hl;
      float m = NEG_INF, l = 0.f;
      float a0=0,a1=0,a2=0,a3=0,a4=0,a5=0,a6=0,a7=0;
      int r = hw;
      uint4 v = {0u, 0u, 0u, 0u};
      if (act && r < n) v = *(const uint4*)(xp + (size_t)r * F_DIM);
      for (; r < n; r += 16) {
        uint4 vc = v;
        int rn = r + 16;
        if (act && rn < n) v = *(const uint4*)(xp + (size_t)rn * F_DIM);  // prefetch
        float x0 = b2f((unsigned short)(vc.x & 0xffff)), x1 = b2f((unsigned short)(vc.x >> 16));
        float x2 = b2f((unsigned short)(vc.y & 0xffff)), x3 = b2f((unsigned short)(vc.y >> 16));
        float x4 = b2f((unsigned short)(vc.z & 0xffff)), x5 = b2f((unsigned short)(vc.z >> 16));
        float x6 = b2f((unsigned short)(vc.w & 0xffff)), x7 = b2f((unsigned short)(vc.w >> 16));
        float p = q0*x0 + q1*x1 + q2*x2 + q3*x3 + q4*x4 + q5*x5 + q6*x6 + q7*x7;
#pragma unroll
        for (int off = 16; off; off >>= 1) p += __shfl_xor(p, off, 32);
        float mn = fmaxf(m, p);
        float fac = __expf(m - mn);       // first iter: exp(-huge)=0
        float w   = __expf(p - mn);
        l  = l * fac + w;
        a0 = a0*fac + w*x0; a1 = a1*fac + w*x1; a2 = a2*fac + w*x2; a3 = a3*fac + w*x3;
        a4 = a4*fac + w*x4; a5 = a5*fac + w*x5; a6 = a6*fac + w*x6; a7 = a7*fac + w*x7;
        m = mn;
      }
      if (hl == 0) redm[hw] = m;
      __syncthreads();
      float M = fmaxf(fmaxf(fmaxf(fmaxf(redm[0], redm[1]), fmaxf(redm[2], redm[3])),
                            fmaxf(fmaxf(redm[4], redm[5]), fmaxf(redm[6], redm[7]))),
                      fmaxf(fmaxf(fmaxf(redm[8], redm[9]), fmaxf(redm[10], redm[11])),
                            fmaxf(fmaxf(redm[12], redm[13]), fmaxf(redm[14], redm[15]))));
      float facw = (m > NEG_INF) ? __expf(m - M) : 0.f;
      if (hl == 0) redl[hw] = l * facw;
      if (act) {
        float* rp = &rpart[hw][8 * hl];
        rp[0] = a0*facw; rp[1] = a1*facw; rp[2] = a2*facw; rp[3] = a3*facw;
        rp[4] = a4*facw; rp[5] = a5*facw; rp[6] = a6*facw; rp[7] = a7*facw;
      }
      __syncthreads();
      float L = redl[0]+redl[1]+redl[2]+redl[3]+redl[4]+redl[5]+redl[6]+redl[7]
              + redl[8]+redl[9]+redl[10]+redl[11]+redl[12]+redl[13]+redl[14]+redl[15];
      float inv = (L > 0.f) ? 1.f / L : 0.f;
      if (tid < F_DIM) {
        float rv = (rpart[0][tid]+rpart[1][tid]+rpart[2][tid]+rpart[3][tid]
                  + rpart[4][tid]+rpart[5][tid]+rpart[6][tid]+rpart[7][tid]
                  + rpart[8][tid]+rpart[9][tid]+rpart[10][tid]+rpart[11][tid]
                  + rpart[12][tid]+rpart[13][tid]+rpart[14][tid]+rpart[15][tid]) * inv;
        if (s < 2) {
          ArowsS[si][200 + tid] = f2bu(rv);
        } else {
          out[(size_t)(seg0 + si) * 400 + 200 + tid] = rv;
        }
      }
      __syncthreads();                    // rpart/redm/redl reused next segment
    }
  }
}

extern "C" void kernel_launch(void* const* d_in, const int* in_sizes, int n_in,
                              void* d_out, int out_size, void* d_ws, size_t ws_size,
                              hipStream_t stream) {
  const float* x    = (const float*)d_in[0];
  const int*   batch= (const int*)d_in[1];
  const float* cosc = (const float*)d_in[2];
  const float* qs0  = (const float*)d_in[3];
  const float* Wih  = (const float*)d_in[4];
  const float* Whh  = (const float*)d_in[5];
  const float* bih  = (const float*)d_in[6];
  const float* bhh  = (const float*)d_in[7];
  char* ws = (char*)d_ws;
  // ws layout (bytes, 16B aligned):
  unsigned short* xb   = (unsigned short*)(ws);               // 131072*200*2 = 52,428,800
  unsigned short* A    = (unsigned short*)(ws + 52428800);    // 2048*608*2   =  2,490,368
  unsigned short* Wc   = (unsigned short*)(ws + 54919168);    // 832*608*2    =  1,011,712
  float*          bsum = (float*)(ws + 64122880);             // 800*4
  int*            soff = (int*)(ws + 64126080);               // 2052*4
  float*          outp = (float*)d_out;

  init_kernel<<<B_SEG, 256, 0, stream>>>(x, batch, cosc, qs0, Wih, Whh, bih, bhh,
                                         xb, A, Wc, bsum, soff);
  main_kernel<<<MAIN_GRID, MAIN_THREADS, 0, stream>>>(xb, soff, A, Wc, bsum, outp);
}

// Round 4
// 306.099 us; speedup vs baseline: 3.3224x; 1.0402x over previous
//
#include <hip/hip_runtime.h>
#include <hip/hip_bf16.h>

#define N_NODES 131072
#define B_SEG   2048
#define F_DIM   200
#define K_DIM   608      // 400 (q_star) + 200 (h) + 8 zero pad = 19*32
#define NEG_INF (-3.4e38f)
#define NMAX    512      // max rows per segment supported (actual max ~110)

typedef __attribute__((ext_vector_type(8))) short bf16x8;
typedef __attribute__((ext_vector_type(4))) float f32x4;

__device__ __forceinline__ float b2f(unsigned short u) {
  union { unsigned int i; float f; } v; v.i = ((unsigned int)u) << 16; return v.f;
}
__device__ __forceinline__ unsigned short f2bu(float f) {
  __hip_bfloat16 h = __float2bfloat16(f);
  return *reinterpret_cast<unsigned short*>(&h);
}
__device__ __forceinline__ float sigmoidf_(float x) { return 1.f / (1.f + __expf(-x)); }
__device__ __forceinline__ float tanhf_(float x) {
  float e = __expf(2.f * x);
  return 1.f - 2.f / (1.f + e);
}

// full-row dot: bf16 row (global) x f32 q (LDS), 4 parallel FMA chains
__device__ __forceinline__ float row_dot(const unsigned short* __restrict__ row,
                                         const float* q) {
  float c0 = 0.f, c1 = 0.f, c2 = 0.f, c3 = 0.f;
#pragma unroll 5
  for (int k = 0; k < 25; k++) {
    uint4 v = *(const uint4*)(row + 8 * k);
    float4 qa = *(const float4*)(q + 8 * k);
    float4 qb = *(const float4*)(q + 8 * k + 4);
    c0 += qa.x * b2f((unsigned short)(v.x & 0xffff))
        + qa.y * b2f((unsigned short)(v.x >> 16));
    c1 += qa.z * b2f((unsigned short)(v.y & 0xffff))
        + qa.w * b2f((unsigned short)(v.y >> 16));
    c2 += qb.x * b2f((unsigned short)(v.z & 0xffff))
        + qb.y * b2f((unsigned short)(v.z >> 16));
    c3 += qb.z * b2f((unsigned short)(v.w & 0xffff))
        + qb.w * b2f((unsigned short)(v.w >> 16));
  }
  return (c0 + c1) + (c2 + c3);
}

// ---- setup (round-0 verbatim): Wc pack, seg offsets, bias sum ----
__global__ __launch_bounds__(256) void setup_kernel(
    const float* __restrict__ Wih, const float* __restrict__ Whh,
    const float* __restrict__ bih, const float* __restrict__ bhh,
    const int* __restrict__ batch, unsigned short* __restrict__ Wc,
    float* __restrict__ bsum, int* __restrict__ seg_off) {
  int bid = blockIdx.x, tid = threadIdx.x;
  if (bid < 1976) {                       // 832*608/256 == 1976 exactly
    int idx = bid * 256 + tid;
    int row = idx / K_DIM, k = idx - row * K_DIM;
    float v = 0.f;
    if (row < 800) {
      if (k < 400)      v = Wih[row * 400 + k];
      else if (k < 600) v = Whh[row * 200 + (k - 400)];
    }
    Wc[idx] = f2bu(v);
  } else if (bid < 1976 + 512) {          // 131072/256 == 512
    int i = (bid - 1976) * 256 + tid;
    int v  = batch[i];
    int pv = (i == 0) ? -1 : batch[i - 1];
    for (int b = pv + 1; b <= v; b++) seg_off[b] = i;
  } else {
    int idx = (bid - 2488) * 256 + tid;
    if (idx < 800) bsum[idx] = bih[idx] + bhh[idx];
    else if (idx == 800) {                // trailing (possibly empty) segments
      int last = batch[N_NODES - 1];
      for (int b = last + 1; b <= B_SEG; b++) seg_off[b] = N_NODES;
    }
  }
}

// ---- convert: grid-stride x(f32) -> xb(bf16), fully coalesced ----
__global__ __launch_bounds__(256) void convert_kernel(
    const float* __restrict__ xf, unsigned short* __restrict__ xb) {
  const int total = N_NODES * F_DIM / 4;          // 6,553,600 float4 groups
  int stride = gridDim.x * 256;
  for (int i = blockIdx.x * 256 + threadIdx.x; i < total; i += stride) {
    float4 v = ((const float4*)xf)[i];
    ushort4 o; o.x = f2bu(v.x); o.y = f2bu(v.y); o.z = f2bu(v.z); o.w = f2bu(v.w);
    ((ushort4*)xb)[i] = o;
  }
}

// ---- a_sit: per-segment cos-weighted column sum (pass-B pattern) + qs0 pack ----
__global__ __launch_bounds__(256) void asit_kernel(
    const unsigned short* __restrict__ xb, const int* __restrict__ seg_off,
    const float* __restrict__ cosc, const float* __restrict__ qs0,
    unsigned short* __restrict__ A) {
  __shared__ float cw[NMAX];
  int b = blockIdx.x, tid = threadIdx.x;
  int start = seg_off[b], end = seg_off[b + 1];
  int n = end - start; if (n > NMAX) n = NMAX;
  unsigned short* Arow = A + (size_t)b * K_DIM;
  for (int r = tid; r < n; r += 256) cw[r] = cosc[start + r];
  if (tid < 100) {                        // qs0 row: 400 f32 -> 400 bf16
    float4 v = *(const float4*)(qs0 + (size_t)b * 400 + 4 * tid);
    ushort4 o; o.x = f2bu(v.x); o.y = f2bu(v.y); o.z = f2bu(v.z); o.w = f2bu(v.w);
    *(ushort4*)(Arow + 4 * tid) = o;
  }
  if (tid < 8) Arow[600 + tid] = 0;
  __syncthreads();
  if (tid < F_DIM) {
    const unsigned short* col = xb + (size_t)start * F_DIM + tid;
    float a0 = 0.f, a1 = 0.f, a2 = 0.f, a3 = 0.f;
    int r = 0;
    for (; r + 4 <= n; r += 4) {
      a0 += cw[r]     * b2f(col[(size_t)(r)     * F_DIM]);
      a1 += cw[r + 1] * b2f(col[(size_t)(r + 1) * F_DIM]);
      a2 += cw[r + 2] * b2f(col[(size_t)(r + 2) * F_DIM]);
      a3 += cw[r + 3] * b2f(col[(size_t)(r + 3) * F_DIM]);
    }
    for (; r < n; r++) a0 += cw[r] * b2f(col[(size_t)r * F_DIM]);
    Arow[400 + tid] = f2bu((a0 + a1) + (a2 + a3));
  }
}

// ---- gates GEMM (round-0 verbatim), barrier-free, BM=32/BN=64: 832 blocks ----
__global__ __launch_bounds__(256) void gemm_gates(
    const unsigned short* __restrict__ A, const unsigned short* __restrict__ W,
    float* __restrict__ gates) {
  int tid = threadIdx.x;
  int bm = blockIdx.x * 32, bn = blockIdx.y * 64;
  int wave = tid >> 6, lane = tid & 63;
  int quad = lane >> 4, col = lane & 15;
  int strip = wave >> 1;                  // 0..1 : 16-row strip
  int tp = (wave & 1) * 2;                // 0 or 2 : N-tile pair
  f32x4 acc[2];
  acc[0] = (f32x4){0.f, 0.f, 0.f, 0.f};
  acc[1] = (f32x4){0.f, 0.f, 0.f, 0.f};
  const unsigned short* Ap = A + (size_t)(bm + strip * 16 + col) * K_DIM + quad * 8;
  const unsigned short* Wp = W + (size_t)(bn + col) * K_DIM + quad * 8;
#pragma unroll
  for (int k0 = 0; k0 < K_DIM; k0 += 32) {
    bf16x8 af = *(const bf16x8*)(Ap + k0);
#pragma unroll
    for (int t = 0; t < 2; t++) {
      bf16x8 bfr = *(const bf16x8*)(Wp + (size_t)(tp + t) * 16 * K_DIM + k0);
      acc[t] = __builtin_amdgcn_mfma_f32_16x16x32_bf16(af, bfr, acc[t], 0, 0, 0);
    }
  }
#pragma unroll
  for (int t = 0; t < 2; t++) {
    int gn = bn + (tp + t) * 16 + col;
    if (gn < 800) {
#pragma unroll
      for (int r = 0; r < 4; r++) {
        int gm = bm + strip * 16 + quad * 4 + r;
        gates[(size_t)gm * 800 + gn] = acc[t][r];
      }
    }
  }
}

// ---- fused LSTM cell + TWO-PASS softmax attention (shuffle-free loops) ----
// Pass A: thread-per-row dot -> e_r; block max; w_r=exp(e_r-M) in LDS; block sum.
// Pass B: thread-per-feature weighted column sum (coalesced), direct output.
__global__ __launch_bounds__(256) void attn2_kernel(
    const unsigned short* __restrict__ xb, const int* __restrict__ seg_off,
    const float* __restrict__ gates, const float* __restrict__ bsum,
    float* __restrict__ cvec, unsigned short* __restrict__ A,
    float* __restrict__ out, int step) {
  __shared__ float q_s[F_DIM];
  __shared__ float w_s[NMAX];
  __shared__ float redm[4], redl[4];
  int b = blockIdx.x, tid = threadIdx.x;
  int start = seg_off[b], end = seg_off[b + 1];
  int n = end - start; if (n > NMAX) n = NMAX;
  unsigned short* Arow = A + (size_t)b * K_DIM;
  // LSTM cell for this segment's 200 features
  if (tid < F_DIM) {
    const float* g = gates + (size_t)b * 800;
    float gi = g[tid]       + bsum[tid];
    float gf = g[200 + tid] + bsum[200 + tid];
    float gg = g[400 + tid] + bsum[400 + tid];
    float go = g[600 + tid] + bsum[600 + tid];
    float cp = (step > 0) ? cvec[(size_t)b * F_DIM + tid] : 0.f;
    float cn = sigmoidf_(gf) * cp + sigmoidf_(gi) * tanhf_(gg);
    float hn = sigmoidf_(go) * tanhf_(cn);
    cvec[(size_t)b * F_DIM + tid] = cn;
    q_s[tid] = hn;
    if (step < 2) {
      unsigned short hb = f2bu(hn);
      Arow[tid] = hb;                     // q part of next q_star
      Arow[400 + tid] = hb;               // hidden for next cell
    } else {
      out[(size_t)b * 400 + tid] = hn;
    }
  }
  __syncthreads();
  // ---- Pass A ----
  float e0 = NEG_INF, e1 = NEG_INF;
  if (tid < n)       e0 = row_dot(xb + (size_t)(start + tid) * F_DIM, q_s);
  if (tid + 256 < n) e1 = row_dot(xb + (size_t)(start + tid + 256) * F_DIM, q_s);
  float mloc = fmaxf(e0, e1);
#pragma unroll
  for (int off = 32; off; off >>= 1) mloc = fmaxf(mloc, __shfl_xor(mloc, off));
  int wv = tid >> 6, lane = tid & 63;
  if (lane == 0) redm[wv] = mloc;
  __syncthreads();
  float M = fmaxf(fmaxf(redm[0], redm[1]), fmaxf(redm[2], redm[3]));
  float wsum = 0.f;
  if (tid < n)       { float w = __expf(e0 - M); w_s[tid] = w;       wsum += w; }
  if (tid + 256 < n) { float w = __expf(e1 - M); w_s[tid + 256] = w; wsum += w; }
#pragma unroll
  for (int off = 32; off; off >>= 1) wsum += __shfl_xor(wsum, off);
  if (lane == 0) redl[wv] = wsum;
  __syncthreads();
  float L = redl[0] + redl[1] + redl[2] + redl[3];
  float inv = (L > 0.f) ? 1.f / L : 0.f;
  // ---- Pass B ----
  if (tid < F_DIM) {
    const unsigned short* col = xb + (size_t)start * F_DIM + tid;
    float a0 = 0.f, a1 = 0.f, a2 = 0.f, a3 = 0.f;
    int r = 0;
    for (; r + 4 <= n; r += 4) {
      a0 += w_s[r]     * b2f(col[(size_t)(r)     * F_DIM]);
      a1 += w_s[r + 1] * b2f(col[(size_t)(r + 1) * F_DIM]);
      a2 += w_s[r + 2] * b2f(col[(size_t)(r + 2) * F_DIM]);
      a3 += w_s[r + 3] * b2f(col[(size_t)(r + 3) * F_DIM]);
    }
    for (; r < n; r++) a0 += w_s[r] * b2f(col[(size_t)r * F_DIM]);
    float rv = ((a0 + a1) + (a2 + a3)) * inv;
    if (step < 2) {
      Arow[200 + tid] = f2bu(rv);
    } else {
      out[(size_t)b * 400 + 200 + tid] = rv;
    }
  }
}

extern "C" void kernel_launch(void* const* d_in, const int* in_sizes, int n_in,
                              void* d_out, int out_size, void* d_ws, size_t ws_size,
                              hipStream_t stream) {
  const float* x    = (const float*)d_in[0];
  const int*   batch= (const int*)d_in[1];
  const float* cosc = (const float*)d_in[2];
  const float* qs0  = (const float*)d_in[3];
  const float* Wih  = (const float*)d_in[4];
  const float* Whh  = (const float*)d_in[5];
  const float* bih  = (const float*)d_in[6];
  const float* bhh  = (const float*)d_in[7];
  char* ws = (char*)d_ws;
  // ws layout (bytes, all 16B aligned), total ~64.2 MB:
  unsigned short* xb   = (unsigned short*)(ws);               // 131072*200*2 = 52,428,800
  unsigned short* A    = (unsigned short*)(ws + 52428800);    // 2048*608*2   =  2,490,368
  unsigned short* Wc   = (unsigned short*)(ws + 54919168);    // 832*608*2    =  1,011,712
  float*          gates= (float*)(ws + 55930880);             // 2048*800*4   =  6,553,600
  float*          cvec = (float*)(ws + 62484480);             // 2048*200*4   =  1,638,400
  float*          bsum = (float*)(ws + 64122880);             // 800*4        =      3,200
  int*            soff = (int*)(ws + 64126080);               // 2052*4       =      8,208
  float*          outp = (float*)d_out;

  setup_kernel<<<2492, 256, 0, stream>>>(Wih, Whh, bih, bhh, batch, Wc, bsum, soff);
  convert_kernel<<<2048, 256, 0, stream>>>(x, xb);
  asit_kernel<<<B_SEG, 256, 0, stream>>>(xb, soff, cosc, qs0, A);
  for (int s = 0; s < 3; s++) {
    gemm_gates<<<dim3(64, 13), 256, 0, stream>>>(A, Wc, gates);
    attn2_kernel<<<B_SEG, 256, 0, stream>>>(xb, soff, gates, bsum, cvec, A, outp, s);
  }
}

// Round 5
// 274.002 us; speedup vs baseline: 3.7115x; 1.1171x over previous
//
#include <hip/hip_runtime.h>
#include <hip/hip_bf16.h>

#define N_NODES 131072
#define B_SEG   2048
#define F_DIM   200
#define K_DIM   608      // 400 (q_star) + 200 (h) + 8 zero pad = 19*32
#define NEG_INF (-3.4e38f)

typedef __attribute__((ext_vector_type(8))) short bf16x8;
typedef __attribute__((ext_vector_type(4))) float f32x4;

__device__ __forceinline__ float b2f(unsigned short u) {
  union { unsigned int i; float f; } v; v.i = ((unsigned int)u) << 16; return v.f;
}
__device__ __forceinline__ unsigned short f2bu(float f) {
  __hip_bfloat16 h = __float2bfloat16(f);
  return *reinterpret_cast<unsigned short*>(&h);
}
__device__ __forceinline__ float sigmoidf_(float x) { return 1.f / (1.f + __expf(-x)); }
__device__ __forceinline__ float tanhf_(float x) {
  float e = __expf(2.f * x);
  return 1.f - 2.f / (1.f + e);
}
// first index i with batch[i] >= target (batch sorted ascending)
__device__ __forceinline__ int lower_bound_batch(const int* __restrict__ batch, int target) {
  int lo = 0, hi = N_NODES;
  while (lo < hi) {
    int mid = (lo + hi) >> 1;
    if (batch[mid] < target) lo = mid + 1; else hi = mid;
  }
  return lo;
}

// ---------------------------------------------------------------------
// init: W pack + bias sum + per-segment bounds (binary search -> seg_off)
//       + x->bf16 + a_sit segment-sum + qs0 pack -> A[2048][608]
// grid 2048 x 256 (block b owns segment b)   [validated in round 3]
// ---------------------------------------------------------------------
__global__ __launch_bounds__(256) void init_kernel(
    const float* __restrict__ xf, const int* __restrict__ batch,
    const float* __restrict__ cosc, const float* __restrict__ qs0,
    const float* __restrict__ Wih, const float* __restrict__ Whh,
    const float* __restrict__ bih, const float* __restrict__ bhh,
    unsigned short* __restrict__ xb, unsigned short* __restrict__ A,
    unsigned short* __restrict__ Wc, float* __restrict__ bsum,
    int* __restrict__ seg_off) {
  __shared__ float rpart[5][F_DIM];
  __shared__ int sb[2];
  int b = blockIdx.x, tid = threadIdx.x;
  if (tid < 2) sb[tid] = lower_bound_batch(batch, b + tid);
  // 2048*256 = 524288 threads >= 832*608 = 505856 (single element each)
  int idx = b * 256 + tid;
  if (idx < 832 * K_DIM) {
    int row = idx / K_DIM, k = idx - row * K_DIM;
    float v = 0.f;
    if (row < 800) {
      if (k < 400)      v = Wih[row * 400 + k];
      else if (k < 600) v = Whh[row * 200 + (k - 400)];
    }
    Wc[idx] = f2bu(v);
  }
  if (idx < 800) bsum[idx] = bih[idx] + bhh[idx];
  __syncthreads();
  int start = sb[0], end = sb[1];
  int n = end - start;
  if (tid == 0) {
    seg_off[b] = start;
    if (b == 0) seg_off[B_SEG] = N_NODES;
  }
  unsigned short* Arow = A + (size_t)b * K_DIM;
  int rgrp = tid / 50, col4 = tid - rgrp * 50;   // rgrp 0..4 active, col4 0..49
  float a0 = 0.f, a1 = 0.f, a2 = 0.f, a3 = 0.f;
  if (rgrp < 5) {
    for (int r = rgrp; r < n; r += 5) {
      float4 v = *(const float4*)(xf + (size_t)(start + r) * F_DIM + 4 * col4);
      ushort4 o; o.x = f2bu(v.x); o.y = f2bu(v.y); o.z = f2bu(v.z); o.w = f2bu(v.w);
      *(ushort4*)(xb + (size_t)(start + r) * F_DIM + 4 * col4) = o;
      float cv = cosc[start + r];
      a0 += cv * b2f(o.x); a1 += cv * b2f(o.y);
      a2 += cv * b2f(o.z); a3 += cv * b2f(o.w);
    }
    rpart[rgrp][4 * col4]     = a0;
    rpart[rgrp][4 * col4 + 1] = a1;
    rpart[rgrp][4 * col4 + 2] = a2;
    rpart[rgrp][4 * col4 + 3] = a3;
  }
  if (tid < 100) {                       // qs0 row: 400 f32 -> 400 bf16
    float4 v = *(const float4*)(qs0 + (size_t)b * 400 + 4 * tid);
    ushort4 o; o.x = f2bu(v.x); o.y = f2bu(v.y); o.z = f2bu(v.z); o.w = f2bu(v.w);
    *(ushort4*)(Arow + 4 * tid) = o;
  }
  if (tid < 8) Arow[600 + tid] = 0;
  __syncthreads();
  if (tid < F_DIM) {
    float acc = rpart[0][tid] + rpart[1][tid] + rpart[2][tid] + rpart[3][tid]
              + rpart[4][tid];
    Arow[400 + tid] = f2bu(acc);
  }
}

// ---- gates GEMM (round-0 verbatim), barrier-free, BM=32/BN=64: 832 blocks ----
__global__ __launch_bounds__(256) void gemm_gates(
    const unsigned short* __restrict__ A, const unsigned short* __restrict__ W,
    float* __restrict__ gates) {
  int tid = threadIdx.x;
  int bm = blockIdx.x * 32, bn = blockIdx.y * 64;
  int wave = tid >> 6, lane = tid & 63;
  int quad = lane >> 4, col = lane & 15;
  int strip = wave >> 1;                  // 0..1 : 16-row strip
  int tp = (wave & 1) * 2;                // 0 or 2 : N-tile pair
  f32x4 acc[2];
  acc[0] = (f32x4){0.f, 0.f, 0.f, 0.f};
  acc[1] = (f32x4){0.f, 0.f, 0.f, 0.f};
  const unsigned short* Ap = A + (size_t)(bm + strip * 16 + col) * K_DIM + quad * 8;
  const unsigned short* Wp = W + (size_t)(bn + col) * K_DIM + quad * 8;
#pragma unroll
  for (int k0 = 0; k0 < K_DIM; k0 += 32) {
    bf16x8 af = *(const bf16x8*)(Ap + k0);
#pragma unroll
    for (int t = 0; t < 2; t++) {
      bf16x8 bfr = *(const bf16x8*)(Wp + (size_t)(tp + t) * 16 * K_DIM + k0);
      acc[t] = __builtin_amdgcn_mfma_f32_16x16x32_bf16(af, bfr, acc[t], 0, 0, 0);
    }
  }
#pragma unroll
  for (int t = 0; t < 2; t++) {
    int gn = bn + (tp + t) * 16 + col;
    if (gn < 800) {
#pragma unroll
      for (int r = 0; r < 4; r++) {
        int gm = bm + strip * 16 + quad * 4 + r;
        gates[(size_t)gm * 800 + gn] = acc[t][r];
      }
    }
  }
}

// ---- fused LSTM cell + online-softmax attention (champion + 1-deep prefetch) ----
__global__ __launch_bounds__(256) void attn_fused(
    const unsigned short* __restrict__ xb, const int* __restrict__ seg_off,
    const float* __restrict__ gates, const float* __restrict__ bsum,
    float* __restrict__ cvec, unsigned short* __restrict__ A,
    float* __restrict__ out, int step) {
  __shared__ float q_s[F_DIM];
  __shared__ float rpart[8][F_DIM];
  __shared__ float redm[8], redl[8];
  int b = blockIdx.x, tid = threadIdx.x;
  int start = seg_off[b], end = seg_off[b + 1];
  int n = end - start;
  unsigned short* Arow = A + (size_t)b * K_DIM;
  // LSTM cell for this segment's 200 features
  if (tid < F_DIM) {
    int f = tid;
    const float* g = gates + (size_t)b * 800;
    float gi = g[f]       + bsum[f];
    float gf = g[200 + f] + bsum[200 + f];
    float gg = g[400 + f] + bsum[400 + f];
    float go = g[600 + f] + bsum[600 + f];
    float cp = (step > 0) ? cvec[(size_t)b * F_DIM + f] : 0.f;
    float cn = sigmoidf_(gf) * cp + sigmoidf_(gi) * tanhf_(gg);
    float hn = sigmoidf_(go) * tanhf_(cn);
    cvec[(size_t)b * F_DIM + f] = cn;
    q_s[f] = hn;
    if (step < 2) {
      unsigned short hb = f2bu(hn);
      Arow[f] = hb;                       // q part of next q_star
      Arow[400 + f] = hb;                 // hidden for next cell
    }
  }
  __syncthreads();
  int wave = tid >> 6, lane = tid & 63;
  int half = lane >> 5, hl = lane & 31;   // 32-lane half-wave
  int hw = wave * 2 + half;               // 0..7 : row owner
  bool act = (hl < 25);                   // 25 lanes x 8 elems = 200 features
  float q0=0,q1=0,q2=0,q3=0,q4=0,q5=0,q6=0,q7=0;
  if (act) {
    q0 = q_s[8*hl];   q1 = q_s[8*hl+1]; q2 = q_s[8*hl+2]; q3 = q_s[8*hl+3];
    q4 = q_s[8*hl+4]; q5 = q_s[8*hl+5]; q6 = q_s[8*hl+6]; q7 = q_s[8*hl+7];
  }
  const unsigned short* xp = xb + (size_t)start * F_DIM + 8 * hl;
  // online softmax: single pass, 1-deep prefetch decouples load latency
  float m = NEG_INF, l = 0.f;
  float a0=0,a1=0,a2=0,a3=0,a4=0,a5=0,a6=0,a7=0;
  int r = hw;
  uint4 v = {0u, 0u, 0u, 0u};
  if (act && r < n) v = *(const uint4*)(xp + (size_t)r * F_DIM);
  for (; r < n; r += 8) {
    uint4 vc = v;
    int rn = r + 8;
    if (act && rn < n) v = *(const uint4*)(xp + (size_t)rn * F_DIM);  // prefetch
    float x0 = b2f((unsigned short)(vc.x & 0xffff)), x1 = b2f((unsigned short)(vc.x >> 16));
    float x2 = b2f((unsigned short)(vc.y & 0xffff)), x3 = b2f((unsigned short)(vc.y >> 16));
    float x4 = b2f((unsigned short)(vc.z & 0xffff)), x5 = b2f((unsigned short)(vc.z >> 16));
    float x6 = b2f((unsigned short)(vc.w & 0xffff)), x7 = b2f((unsigned short)(vc.w >> 16));
    float p = act ? (q0*x0 + q1*x1 + q2*x2 + q3*x3 + q4*x4 + q5*x5 + q6*x6 + q7*x7) : 0.f;
    // in-segment butterfly over the 32-lane half: every lane gets the row dot
#pragma unroll
    for (int off = 16; off; off >>= 1) p += __shfl_xor(p, off, 32);
    float e = p;
    float mn = fmaxf(m, e);
    float fac = __expf(m - mn);           // first iter: exp(-inf)=0
    float w  = __expf(e - mn);
    l  = l * fac + w;
    a0 = a0*fac + w*x0; a1 = a1*fac + w*x1; a2 = a2*fac + w*x2; a3 = a3*fac + w*x3;
    a4 = a4*fac + w*x4; a5 = a5*fac + w*x5; a6 = a6*fac + w*x6; a7 = a7*fac + w*x7;
    m = mn;
  }
  // cross-half-wave combine: 8 (m,l,a) triples
  if (hl == 0) redm[hw] = m;
  __syncthreads();
  float M = fmaxf(fmaxf(fmaxf(redm[0], redm[1]), fmaxf(redm[2], redm[3])),
                  fmaxf(fmaxf(redm[4], redm[5]), fmaxf(redm[6], redm[7])));
  float facw = (m > NEG_INF) ? __expf(m - M) : 0.f;
  if (hl == 0) redl[hw] = l * facw;
  if (act) {
    float* rp = &rpart[hw][8 * hl];
    rp[0] = a0*facw; rp[1] = a1*facw; rp[2] = a2*facw; rp[3] = a3*facw;
    rp[4] = a4*facw; rp[5] = a5*facw; rp[6] = a6*facw; rp[7] = a7*facw;
  }
  __syncthreads();
  float L = redl[0]+redl[1]+redl[2]+redl[3]+redl[4]+redl[5]+redl[6]+redl[7];
  float inv = (L > 0.f) ? 1.f / L : 0.f;
  if (tid < F_DIM) {
    float rv = (rpart[0][tid]+rpart[1][tid]+rpart[2][tid]+rpart[3][tid]
              + rpart[4][tid]+rpart[5][tid]+rpart[6][tid]+rpart[7][tid]) * inv;
    if (step < 2) {
      Arow[200 + tid] = f2bu(rv);
    } else {
      out[(size_t)b * 400 + tid]       = q_s[tid];
      out[(size_t)b * 400 + 200 + tid] = rv;
    }
  }
}

extern "C" void kernel_launch(void* const* d_in, const int* in_sizes, int n_in,
                              void* d_out, int out_size, void* d_ws, size_t ws_size,
                              hipStream_t stream) {
  const float* x    = (const float*)d_in[0];
  const int*   batch= (const int*)d_in[1];
  const float* cosc = (const float*)d_in[2];
  const float* qs0  = (const float*)d_in[3];
  const float* Wih  = (const float*)d_in[4];
  const float* Whh  = (const float*)d_in[5];
  const float* bih  = (const float*)d_in[6];
  const float* bhh  = (const float*)d_in[7];
  char* ws = (char*)d_ws;
  // ws layout (bytes, all 16B aligned), total ~64.2 MB:
  unsigned short* xb   = (unsigned short*)(ws);               // 131072*200*2 = 52,428,800
  unsigned short* A    = (unsigned short*)(ws + 52428800);    // 2048*608*2   =  2,490,368
  unsigned short* Wc   = (unsigned short*)(ws + 54919168);    // 832*608*2    =  1,011,712
  float*          gates= (float*)(ws + 55930880);             // 2048*800*4   =  6,553,600
  float*          cvec = (float*)(ws + 62484480);             // 2048*200*4   =  1,638,400
  float*          bsum = (float*)(ws + 64122880);             // 800*4        =      3,200
  int*            soff = (int*)(ws + 64126080);               // 2052*4       =      8,208
  float*          outp = (float*)d_out;

  init_kernel<<<B_SEG, 256, 0, stream>>>(x, batch, cosc, qs0, Wih, Whh, bih, bhh,
                                         xb, A, Wc, bsum, soff);
  for (int s = 0; s < 3; s++) {
    gemm_gates<<<dim3(64, 13), 256, 0, stream>>>(A, Wc, gates);
    attn_fused<<<B_SEG, 256, 0, stream>>>(xb, soff, gates, bsum, cvec, A, outp, s);
  }
}